// Round 1
// baseline (436.348 us; speedup 1.0000x reference)
//
#include <hip/hip_runtime.h>
#include <hip/hip_bf16.h>

#define C 256

typedef __attribute__((ext_vector_type(8))) short bf16x8;
typedef __attribute__((ext_vector_type(4))) float f32x4;
typedef __attribute__((ext_vector_type(4))) unsigned short us4;

__device__ __forceinline__ float bf2f(unsigned short u) {
  return __uint_as_float(((unsigned int)u) << 16);
}
__device__ __forceinline__ unsigned short f2bf(float f) {
  unsigned int x = __float_as_uint(f);
  unsigned int lsb = (x >> 16) & 1u;
  x += 0x7fffu + lsb;  // round-to-nearest-even
  return (unsigned short)(x >> 16);
}

// WT[m][c][k] = bf16(W_m[k][c]); m=0 -> root, m=1..4 -> rel r
__global__ void k_prep_w(const float* __restrict__ rel, const float* __restrict__ root,
                         unsigned short* __restrict__ WT) {
  int b = blockIdx.x;          // 0..5*256-1
  int m = b >> 8;
  int c = b & 255;
  int k = threadIdx.x;
  const float* W = (m == 0) ? root : (rel + (size_t)(m - 1) * C * C);
  WT[(size_t)m * C * C + (size_t)c * C + k] = f2bf(W[(size_t)k * C + c]);
}

__global__ void k_cvt_x(const float* __restrict__ X, unsigned short* __restrict__ Xbf,
                        int n_elem, int total) {
  int i = (blockIdx.x * blockDim.x + threadIdx.x) * 4;
  if (i >= total) return;
  us4 o;
  if (i < n_elem) {
    const float4 v = *reinterpret_cast<const float4*>(X + i);
    o.x = f2bf(v.x); o.y = f2bf(v.y); o.z = f2bf(v.z); o.w = f2bf(v.w);
  } else {
    o.x = 0; o.y = 0; o.z = 0; o.w = 0;   // zero pad rows
  }
  *reinterpret_cast<us4*>(Xbf + i) = o;
}

__global__ void k_hist(const int* __restrict__ edst, int* __restrict__ cnt, int E) {
  int e = blockIdx.x * blockDim.x + threadIdx.x;
  if (e < E) atomicAdd(cnt + edst[e], 1);
}

__global__ void k_scan1(const int* __restrict__ cnt, int* __restrict__ rp,
                        int* __restrict__ bsum, int n) {
  __shared__ int s[512];
  int t = threadIdx.x;
  int i = blockIdx.x * 512 + t;
  int v = (i < n) ? cnt[i] : 0;
  s[t] = v;
  __syncthreads();
  for (int off = 1; off < 512; off <<= 1) {
    int add = (t >= off) ? s[t - off] : 0;
    __syncthreads();
    s[t] += add;
    __syncthreads();
  }
  if (i < n) rp[i] = s[t] - v;      // exclusive within block
  if (t == 511) bsum[blockIdx.x] = s[511];
}

__global__ void k_scan2(const int* __restrict__ bsum, int* __restrict__ boff,
                        int* __restrict__ rp, int nb, int n) {
  if (threadIdx.x == 0) {
    int run = 0;
    for (int b = 0; b < nb; ++b) { boff[b] = run; run += bsum[b]; }
    rp[n] = run;   // == E
  }
}

__global__ void k_scan3(int* __restrict__ rp, const int* __restrict__ boff, int n) {
  int i = blockIdx.x * 512 + threadIdx.x;
  if (i < n) rp[i] += boff[blockIdx.x];
}

__global__ void k_fill(const int* __restrict__ esrc, const int* __restrict__ edst,
                       const int* __restrict__ etype, int* __restrict__ cursor,
                       unsigned int* __restrict__ sorted, int E) {
  int e = blockIdx.x * blockDim.x + threadIdx.x;
  if (e >= E) return;
  int d = edst[e];
  int pos = atomicAdd(cursor + d, 1);
  sorted[pos] = (unsigned int)esrc[e] | ((unsigned int)etype[e] << 28);
}

// One wave per dst node: per-relation fp32 mean-accumulate of bf16 X rows, write bf16.
__global__ void k_gather(const unsigned short* __restrict__ Xbf,
                         const unsigned int* __restrict__ sorted,
                         const int* __restrict__ rp,
                         unsigned short* __restrict__ agm,
                         int N, int rowsPad) {
  int wave = threadIdx.x >> 6;
  int lane = threadIdx.x & 63;
  int dst = blockIdx.x * 4 + wave;
  if (dst >= rowsPad) return;

  if (dst >= N) {   // pad rows: write zeros so GEMM reads finite data
    us4 z; z.x = 0; z.y = 0; z.z = 0; z.w = 0;
    for (int r = 0; r < 4; ++r)
      *reinterpret_cast<us4*>(agm + ((size_t)r * rowsPad + dst) * C + lane * 4) = z;
    return;
  }

  float4 a0 = make_float4(0, 0, 0, 0), a1 = a0, a2 = a0, a3 = a0;
  int c0 = 0, c1 = 0, c2 = 0, c3 = 0;
  int s = rp[dst], e2 = rp[dst + 1];
  const us4* Xv = reinterpret_cast<const us4*>(Xbf);
  for (int e = s; e < e2; ++e) {
    unsigned int u = sorted[e];
    int src = (int)(u & 0x0FFFFFFFu);
    int r = (int)(u >> 28);
    us4 v = Xv[(size_t)src * 64 + lane];
    float f0 = bf2f(v.x), f1 = bf2f(v.y), f2 = bf2f(v.z), f3 = bf2f(v.w);
    switch (r) {   // wave-uniform branch (r same for all 64 lanes)
      case 0: a0.x += f0; a0.y += f1; a0.z += f2; a0.w += f3; ++c0; break;
      case 1: a1.x += f0; a1.y += f1; a1.z += f2; a1.w += f3; ++c1; break;
      case 2: a2.x += f0; a2.y += f1; a2.z += f2; a2.w += f3; ++c2; break;
      default: a3.x += f0; a3.y += f1; a3.z += f2; a3.w += f3; ++c3; break;
    }
  }
  float s0 = 1.0f / (float)max(c0, 1);
  float s1 = 1.0f / (float)max(c1, 1);
  float s2 = 1.0f / (float)max(c2, 1);
  float s3 = 1.0f / (float)max(c3, 1);
  us4 o;
  size_t base = (size_t)dst * C + lane * 4;
  o.x = f2bf(a0.x * s0); o.y = f2bf(a0.y * s0); o.z = f2bf(a0.z * s0); o.w = f2bf(a0.w * s0);
  *reinterpret_cast<us4*>(agm + base) = o;
  o.x = f2bf(a1.x * s1); o.y = f2bf(a1.y * s1); o.z = f2bf(a1.z * s1); o.w = f2bf(a1.w * s1);
  *reinterpret_cast<us4*>(agm + (size_t)rowsPad * C + base) = o;
  o.x = f2bf(a2.x * s2); o.y = f2bf(a2.y * s2); o.z = f2bf(a2.z * s2); o.w = f2bf(a2.w * s2);
  *reinterpret_cast<us4*>(agm + (size_t)2 * rowsPad * C + base) = o;
  o.x = f2bf(a3.x * s3); o.y = f2bf(a3.y * s3); o.z = f2bf(a3.z * s3); o.w = f2bf(a3.w * s3);
  *reinterpret_cast<us4*>(agm + (size_t)3 * rowsPad * C + base) = o;
}

// Fused 5-matrix GEMM: out = Xbf@WT0 + sum_r agm_r@WT(r+1) + bias.
// Wave tile: 32 rows x 128 cols (2x8 frags of 16x16), block = 4 waves = 64 rows x 256 cols.
__global__ __launch_bounds__(256) void k_gemm(const unsigned short* __restrict__ Xbf,
                                              const unsigned short* __restrict__ agm,
                                              const unsigned short* __restrict__ WT,
                                              const float* __restrict__ bias,
                                              float* __restrict__ out, int N, int rowsPad) {
  int wave = threadIdx.x >> 6, lane = threadIdx.x & 63;
  int rowBase = blockIdx.x * 64 + (wave & 1) * 32;
  int colBase = (wave >> 1) * 128;
  int lrow = lane & 15;
  int lk = (lane >> 4) * 8;

  f32x4 acc[2][8];
#pragma unroll
  for (int i = 0; i < 2; ++i)
#pragma unroll
    for (int j = 0; j < 8; ++j) {
      f32x4 z; z[0] = 0.f; z[1] = 0.f; z[2] = 0.f; z[3] = 0.f;
      acc[i][j] = z;
    }

#pragma unroll 1
  for (int m = 0; m < 5; ++m) {
    const unsigned short* A = (m == 0) ? Xbf : (agm + (size_t)(m - 1) * rowsPad * C);
    const unsigned short* B = WT + (size_t)m * C * C;
#pragma unroll 1
    for (int ks = 0; ks < 8; ++ks) {
      int k0 = ks * 32 + lk;
      bf16x8 af[2];
#pragma unroll
      for (int rt = 0; rt < 2; ++rt)
        af[rt] = *reinterpret_cast<const bf16x8*>(A + (size_t)(rowBase + rt * 16 + lrow) * C + k0);
#pragma unroll
      for (int ct = 0; ct < 8; ++ct) {
        bf16x8 bf = *reinterpret_cast<const bf16x8*>(B + (size_t)(colBase + ct * 16 + lrow) * C + k0);
        acc[0][ct] = __builtin_amdgcn_mfma_f32_16x16x32_bf16(af[0], bf, acc[0][ct], 0, 0, 0);
        acc[1][ct] = __builtin_amdgcn_mfma_f32_16x16x32_bf16(af[1], bf, acc[1][ct], 0, 0, 0);
      }
    }
  }

  int r0 = (lane >> 4) * 4;
#pragma unroll
  for (int rt = 0; rt < 2; ++rt) {
#pragma unroll
    for (int reg = 0; reg < 4; ++reg) {
      int row = rowBase + rt * 16 + r0 + reg;
      if (row < N) {
#pragma unroll
        for (int ct = 0; ct < 8; ++ct) {
          int col = colBase + ct * 16 + lrow;
          out[(size_t)row * C + col] = acc[rt][ct][reg] + bias[col];
        }
      }
    }
  }
}

// Gate: a = sigmoid(u0.w1 + x.w2 + b); h = tanh(u0)*a + x*(1-a). One wave per node, in place.
__global__ void k_gate(const float* __restrict__ X, const float* __restrict__ aw,
                       const float* __restrict__ ab, float* __restrict__ out, int N) {
  int wave = threadIdx.x >> 6, lane = threadIdx.x & 63;
  int node = blockIdx.x * 4 + wave;
  if (node >= N) return;
  const float4* u4 = reinterpret_cast<const float4*>(out + (size_t)node * C);
  const float4* x4 = reinterpret_cast<const float4*>(X + (size_t)node * C);
  float4 u = u4[lane], x = x4[lane];
  const float4* w = reinterpret_cast<const float4*>(aw);
  float4 w1 = w[lane], w2 = w[64 + lane];
  float p = u.x * w1.x + u.y * w1.y + u.z * w1.z + u.w * w1.w
          + x.x * w2.x + x.y * w2.y + x.z * w2.z + x.w * w2.w;
#pragma unroll
  for (int off = 32; off >= 1; off >>= 1) p += __shfl_xor(p, off);
  float a = 1.0f / (1.0f + expf(-(p + ab[0])));
  float b = 1.0f - a;
  float4 h;
  h.x = tanhf(u.x) * a + x.x * b;
  h.y = tanhf(u.y) * a + x.y * b;
  h.z = tanhf(u.z) * a + x.z * b;
  h.w = tanhf(u.w) * a + x.w * b;
  reinterpret_cast<float4*>(out + (size_t)node * C)[lane] = h;
}

extern "C" void kernel_launch(void* const* d_in, const int* in_sizes, int n_in,
                              void* d_out, int out_size, void* d_ws, size_t ws_size,
                              hipStream_t stream) {
  const float* X     = (const float*)d_in[0];
  const int*   eidx  = (const int*)d_in[1];
  const int*   etype = (const int*)d_in[2];
  const float* rel   = (const float*)d_in[3];
  const float* root  = (const float*)d_in[4];
  const float* bias  = (const float*)d_in[5];
  const float* aw    = (const float*)d_in[6];
  const float* ab    = (const float*)d_in[7];
  float* out = (float*)d_out;

  int N = in_sizes[0] / C;        // 50000
  int E = in_sizes[2];            // 800000
  int rowsPad = ((N + 63) / 64) * 64;   // 50048
  const int* esrc = eidx;
  const int* edst = eidx + E;

  char* w = (char*)d_ws;
  size_t off = 0;
  auto alloc = [&](size_t bytes) -> void* {
    void* p = w + off;
    off += (bytes + 255) & ~(size_t)255;
    return p;
  };
  unsigned short* Xbf  = (unsigned short*)alloc((size_t)rowsPad * C * 2);
  unsigned short* agm  = (unsigned short*)alloc((size_t)4 * rowsPad * C * 2);
  unsigned short* WT   = (unsigned short*)alloc((size_t)5 * C * C * 2);
  int* cnt    = (int*)alloc((size_t)N * 4);
  int* rp     = (int*)alloc((size_t)(N + 1) * 4);
  int* cursor = (int*)alloc((size_t)N * 4);
  int* bsum   = (int*)alloc(1024);
  int* boff   = (int*)alloc(1024);
  unsigned int* sorted = (unsigned int*)alloc((size_t)E * 4);

  hipMemsetAsync(cnt, 0, (size_t)N * 4, stream);
  k_prep_w<<<5 * C, C, 0, stream>>>(rel, root, WT);
  k_cvt_x<<<(rowsPad * C / 4 + 255) / 256, 256, 0, stream>>>(X, Xbf, N * C, rowsPad * C);
  k_hist<<<(E + 255) / 256, 256, 0, stream>>>(edst, cnt, E);
  int NB = (N + 511) / 512;
  k_scan1<<<NB, 512, 0, stream>>>(cnt, rp, bsum, N);
  k_scan2<<<1, 64, 0, stream>>>(bsum, boff, rp, NB, N);
  k_scan3<<<NB, 512, 0, stream>>>(rp, boff, N);
  hipMemcpyAsync(cursor, rp, (size_t)N * 4, hipMemcpyDeviceToDevice, stream);
  k_fill<<<(E + 255) / 256, 256, 0, stream>>>(esrc, edst, etype, cursor, sorted, E);
  k_gather<<<rowsPad / 4, 256, 0, stream>>>(Xbf, sorted, rp, agm, N, rowsPad);
  k_gemm<<<rowsPad / 64, 256, 0, stream>>>(Xbf, agm, WT, bias, out, N, rowsPad);
  k_gate<<<(N + 3) / 4, 256, 0, stream>>>(X, aw, ab, out, N);
}

// Round 2
// 318.733 us; speedup vs baseline: 1.3690x; 1.3690x over previous
//
#include <hip/hip_runtime.h>
#include <hip/hip_bf16.h>

#define C 256
#define BM 128
#define BN 128
#define BK 32
#define NSTEP 40   // K = 5*256 / 32

typedef __attribute__((ext_vector_type(8))) short bf16x8;
typedef __attribute__((ext_vector_type(4))) float f32x4;
typedef __attribute__((ext_vector_type(4))) unsigned short us4;

#define GLL16(g, l)                                                         \
  __builtin_amdgcn_global_load_lds(                                         \
      (const __attribute__((address_space(1))) void*)(g),                   \
      (__attribute__((address_space(3))) void*)(l), 16, 0, 0)

__device__ __forceinline__ float bf2f(unsigned short u) {
  return __uint_as_float(((unsigned int)u) << 16);
}
__device__ __forceinline__ unsigned short f2bf(float f) {
  unsigned int x = __float_as_uint(f);
  unsigned int lsb = (x >> 16) & 1u;
  x += 0x7fffu + lsb;  // round-to-nearest-even
  return (unsigned short)(x >> 16);
}

// WT[m][c][k] = bf16(W_m[k][c]); m=0 -> root, m=1..4 -> rel r
__global__ void k_prep_w(const float* __restrict__ rel, const float* __restrict__ root,
                         unsigned short* __restrict__ WT) {
  int b = blockIdx.x;
  int m = b >> 8;
  int c = b & 255;
  int k = threadIdx.x;
  const float* W = (m == 0) ? root : (rel + (size_t)(m - 1) * C * C);
  WT[(size_t)m * C * C + (size_t)c * C + k] = f2bf(W[(size_t)k * C + c]);
}

__global__ void k_cvt_x(const float* __restrict__ X, unsigned short* __restrict__ Xbf,
                        int n_elem, int total) {
  int i = (blockIdx.x * blockDim.x + threadIdx.x) * 4;
  if (i >= total) return;
  us4 o;
  if (i < n_elem) {
    const float4 v = *reinterpret_cast<const float4*>(X + i);
    o.x = f2bf(v.x); o.y = f2bf(v.y); o.z = f2bf(v.z); o.w = f2bf(v.w);
  } else {
    o.x = 0; o.y = 0; o.z = 0; o.w = 0;   // zero pad rows
  }
  *reinterpret_cast<us4*>(Xbf + i) = o;
}

__global__ void k_hist(const int* __restrict__ edst, int* __restrict__ cnt, int E) {
  int e = blockIdx.x * blockDim.x + threadIdx.x;
  if (e < E) atomicAdd(cnt + edst[e], 1);
}

__global__ void k_scan1(const int* __restrict__ cnt, int* __restrict__ rp,
                        int* __restrict__ bsum, int n) {
  __shared__ int s[512];
  int t = threadIdx.x;
  int i = blockIdx.x * 512 + t;
  int v = (i < n) ? cnt[i] : 0;
  s[t] = v;
  __syncthreads();
  for (int off = 1; off < 512; off <<= 1) {
    int add = (t >= off) ? s[t - off] : 0;
    __syncthreads();
    s[t] += add;
    __syncthreads();
  }
  if (i < n) rp[i] = s[t] - v;
  if (t == 511) bsum[blockIdx.x] = s[511];
}

__global__ void k_scan2(const int* __restrict__ bsum, int* __restrict__ boff,
                        int* __restrict__ rp, int nb, int n) {
  if (threadIdx.x == 0) {
    int run = 0;
    for (int b = 0; b < nb; ++b) { boff[b] = run; run += bsum[b]; }
    rp[n] = run;
  }
}

__global__ void k_scan3(int* __restrict__ rp, const int* __restrict__ boff, int n) {
  int i = blockIdx.x * 512 + threadIdx.x;
  if (i < n) rp[i] += boff[blockIdx.x];
}

__global__ void k_fill(const int* __restrict__ esrc, const int* __restrict__ edst,
                       const int* __restrict__ etype, int* __restrict__ cursor,
                       unsigned int* __restrict__ sorted, int E) {
  int e = blockIdx.x * blockDim.x + threadIdx.x;
  if (e >= E) return;
  int d = edst[e];
  int pos = atomicAdd(cursor + d, 1);
  sorted[pos] = (unsigned int)esrc[e] | ((unsigned int)etype[e] << 28);
}

// One wave per dst node: per-relation fp32 mean-accumulate of bf16 X rows, write bf16.
__global__ void k_gather(const unsigned short* __restrict__ Xbf,
                         const unsigned int* __restrict__ sorted,
                         const int* __restrict__ rp,
                         unsigned short* __restrict__ agm,
                         int N, int rowsPad) {
  int wave = threadIdx.x >> 6;
  int lane = threadIdx.x & 63;
  int dst = blockIdx.x * 4 + wave;
  if (dst >= rowsPad) return;

  if (dst >= N) {   // pad rows: zero so GEMM reads finite data
    us4 z; z.x = 0; z.y = 0; z.z = 0; z.w = 0;
    for (int r = 0; r < 4; ++r)
      *reinterpret_cast<us4*>(agm + ((size_t)r * rowsPad + dst) * C + lane * 4) = z;
    return;
  }

  float4 a0 = make_float4(0, 0, 0, 0), a1 = a0, a2 = a0, a3 = a0;
  int c0 = 0, c1 = 0, c2 = 0, c3 = 0;
  int s = rp[dst], e2 = rp[dst + 1];
  const us4* Xv = reinterpret_cast<const us4*>(Xbf);
  for (int e = s; e < e2; ++e) {
    unsigned int u = sorted[e];
    int src = (int)(u & 0x0FFFFFFFu);
    int r = (int)(u >> 28);
    us4 v = Xv[(size_t)src * 64 + lane];
    float f0 = bf2f(v.x), f1 = bf2f(v.y), f2 = bf2f(v.z), f3 = bf2f(v.w);
    switch (r) {   // wave-uniform branch
      case 0: a0.x += f0; a0.y += f1; a0.z += f2; a0.w += f3; ++c0; break;
      case 1: a1.x += f0; a1.y += f1; a1.z += f2; a1.w += f3; ++c1; break;
      case 2: a2.x += f0; a2.y += f1; a2.z += f2; a2.w += f3; ++c2; break;
      default: a3.x += f0; a3.y += f1; a3.z += f2; a3.w += f3; ++c3; break;
    }
  }
  float s0 = 1.0f / (float)max(c0, 1);
  float s1 = 1.0f / (float)max(c1, 1);
  float s2 = 1.0f / (float)max(c2, 1);
  float s3 = 1.0f / (float)max(c3, 1);
  us4 o;
  size_t base = (size_t)dst * C + lane * 4;
  o.x = f2bf(a0.x * s0); o.y = f2bf(a0.y * s0); o.z = f2bf(a0.z * s0); o.w = f2bf(a0.w * s0);
  *reinterpret_cast<us4*>(agm + base) = o;
  o.x = f2bf(a1.x * s1); o.y = f2bf(a1.y * s1); o.z = f2bf(a1.z * s1); o.w = f2bf(a1.w * s1);
  *reinterpret_cast<us4*>(agm + (size_t)rowsPad * C + base) = o;
  o.x = f2bf(a2.x * s2); o.y = f2bf(a2.y * s2); o.z = f2bf(a2.z * s2); o.w = f2bf(a2.w * s2);
  *reinterpret_cast<us4*>(agm + (size_t)2 * rowsPad * C + base) = o;
  o.x = f2bf(a3.x * s3); o.y = f2bf(a3.y * s3); o.z = f2bf(a3.z * s3); o.w = f2bf(a3.w * s3);
  *reinterpret_cast<us4*>(agm + (size_t)3 * rowsPad * C + base) = o;
}

// One K=1280 GEMM: out = A_all @ WT^T + bias, A_all = [5][rowsPad][256] bf16.
// m97 structure: 128x128 tile, BK=32, global_load_lds staging, 2-barrier K-loop.
// LDS tiles [128][32] bf16 with 16B-granule XOR swizzle (granule ^= row&3):
// linear LDS dest (global_load_lds), inverse-swizzled global src, swizzled ds_read.
__global__ __launch_bounds__(256) void k_gemm(const unsigned short* __restrict__ Aall,
                                              const unsigned short* __restrict__ WT,
                                              const float* __restrict__ bias,
                                              float* __restrict__ out, int N, int rowsPad) {
  __shared__ unsigned short lds_a[BM * BK];
  __shared__ unsigned short lds_b[BN * BK];
  int tid = threadIdx.x;
  int wave = tid >> 6, lane = tid & 63;
  int mblk = blockIdx.x >> 1, nblk = blockIdx.x & 1;
  int row0 = mblk * BM, col0 = nblk * BN;
  int wr = wave >> 1, wc = wave & 1;

  // staging geometry (loop-invariant): each wave stages 2 chunks of A + 2 of B
  int rowS[2], lg8[2];
#pragma unroll
  for (int c2 = 0; c2 < 2; ++c2) {
    int off = (wave * 2 + c2) * 1024 + lane * 16;   // phys byte in tile
    int r = off >> 6;                                // tile row (64B rows)
    int lg = ((off >> 4) & 3) ^ (r & 3);             // logical 16B granule
    rowS[c2] = r;
    lg8[c2] = lg * 8;                                // element offset
  }

  // ds_read byte offsets (loop-invariant, swizzled)
  int aoff[4], boff[4];
  int kb = (lane >> 4) * 16;
#pragma unroll
  for (int i = 0; i < 4; ++i) {
    int ar = wr * 64 + i * 16 + (lane & 15);
    aoff[i] = ar * 64 + (kb ^ ((ar & 3) << 4));
    int bc = wc * 64 + i * 16 + (lane & 15);
    boff[i] = bc * 64 + (kb ^ ((bc & 3) << 4));
  }

  f32x4 acc[4][4];
#pragma unroll
  for (int i = 0; i < 4; ++i)
#pragma unroll
    for (int j = 0; j < 4; ++j) {
      f32x4 z; z[0] = 0.f; z[1] = 0.f; z[2] = 0.f; z[3] = 0.f;
      acc[i][j] = z;
    }

#pragma unroll 1
  for (int ks = 0; ks < NSTEP; ++ks) {
    int m = ks >> 3;
    int kk = (ks & 7) * BK;
    const unsigned short* Ab = Aall + (size_t)m * rowsPad * C + kk;
    const unsigned short* Bb = WT + (size_t)m * C * C + kk;
#pragma unroll
    for (int c2 = 0; c2 < 2; ++c2) {
      const unsigned short* sa = Ab + (size_t)(row0 + rowS[c2]) * C + lg8[c2];
      const unsigned short* sb = Bb + (size_t)(col0 + rowS[c2]) * C + lg8[c2];
      GLL16(sa, (char*)lds_a + (wave * 2 + c2) * 1024);
      GLL16(sb, (char*)lds_b + (wave * 2 + c2) * 1024);
    }
    __syncthreads();   // drains vmcnt -> staged tiles visible
    bf16x8 af[4], bfr[4];
#pragma unroll
    for (int i = 0; i < 4; ++i) {
      af[i]  = *reinterpret_cast<const bf16x8*>((const char*)lds_a + aoff[i]);
      bfr[i] = *reinterpret_cast<const bf16x8*>((const char*)lds_b + boff[i]);
    }
#pragma unroll
    for (int mr = 0; mr < 4; ++mr)
#pragma unroll
      for (int nc = 0; nc < 4; ++nc)
        acc[mr][nc] = __builtin_amdgcn_mfma_f32_16x16x32_bf16(af[mr], bfr[nc], acc[mr][nc], 0, 0, 0);
    __syncthreads();   // all waves done reading before next overwrite
  }

  int lcol = lane & 15, lrow4 = (lane >> 4) * 4;
#pragma unroll
  for (int mr = 0; mr < 4; ++mr) {
#pragma unroll
    for (int reg = 0; reg < 4; ++reg) {
      int rowg = row0 + wr * 64 + mr * 16 + lrow4 + reg;
      if (rowg < N) {
#pragma unroll
        for (int nc = 0; nc < 4; ++nc) {
          int colg = col0 + wc * 64 + nc * 16 + lcol;
          out[(size_t)rowg * C + colg] = acc[mr][nc][reg] + bias[colg];
        }
      }
    }
  }
}

// Gate: a = sigmoid(u0.w1 + x.w2 + b); h = tanh(u0)*a + x*(1-a). One wave per node, in place.
__global__ void k_gate(const float* __restrict__ X, const float* __restrict__ aw,
                       const float* __restrict__ ab, float* __restrict__ out, int N) {
  int wave = threadIdx.x >> 6, lane = threadIdx.x & 63;
  int node = blockIdx.x * 4 + wave;
  if (node >= N) return;
  const float4* u4 = reinterpret_cast<const float4*>(out + (size_t)node * C);
  const float4* x4 = reinterpret_cast<const float4*>(X + (size_t)node * C);
  float4 u = u4[lane], x = x4[lane];
  const float4* w = reinterpret_cast<const float4*>(aw);
  float4 w1 = w[lane], w2 = w[64 + lane];
  float p = u.x * w1.x + u.y * w1.y + u.z * w1.z + u.w * w1.w
          + x.x * w2.x + x.y * w2.y + x.z * w2.z + x.w * w2.w;
#pragma unroll
  for (int off = 32; off >= 1; off >>= 1) p += __shfl_xor(p, off);
  float a = 1.0f / (1.0f + expf(-(p + ab[0])));
  float b = 1.0f - a;
  float4 h;
  h.x = tanhf(u.x) * a + x.x * b;
  h.y = tanhf(u.y) * a + x.y * b;
  h.z = tanhf(u.z) * a + x.z * b;
  h.w = tanhf(u.w) * a + x.w * b;
  reinterpret_cast<float4*>(out + (size_t)node * C)[lane] = h;
}

extern "C" void kernel_launch(void* const* d_in, const int* in_sizes, int n_in,
                              void* d_out, int out_size, void* d_ws, size_t ws_size,
                              hipStream_t stream) {
  const float* X     = (const float*)d_in[0];
  const int*   eidx  = (const int*)d_in[1];
  const int*   etype = (const int*)d_in[2];
  const float* rel   = (const float*)d_in[3];
  const float* root  = (const float*)d_in[4];
  const float* bias  = (const float*)d_in[5];
  const float* aw    = (const float*)d_in[6];
  const float* ab    = (const float*)d_in[7];
  float* out = (float*)d_out;

  int N = in_sizes[0] / C;              // 50000
  int E = in_sizes[2];                  // 800000
  int rowsPad = ((N + 127) / 128) * 128;  // 50048
  const int* esrc = eidx;
  const int* edst = eidx + E;

  char* w = (char*)d_ws;
  size_t off = 0;
  auto alloc = [&](size_t bytes) -> void* {
    void* p = w + off;
    off += (bytes + 255) & ~(size_t)255;
    return p;
  };
  // A_all = [5][rowsPad][C] bf16; m=0 is X, m=1..4 are per-relation means
  unsigned short* Aall = (unsigned short*)alloc((size_t)5 * rowsPad * C * 2);
  unsigned short* Xbf  = Aall;
  unsigned short* agm  = Aall + (size_t)rowsPad * C;
  unsigned short* WT   = (unsigned short*)alloc((size_t)5 * C * C * 2);
  int* cnt    = (int*)alloc((size_t)N * 4);
  int* rp     = (int*)alloc((size_t)(N + 1) * 4);
  int* cursor = (int*)alloc((size_t)N * 4);
  int* bsum   = (int*)alloc(1024);
  int* boffb  = (int*)alloc(1024);
  unsigned int* sorted = (unsigned int*)alloc((size_t)E * 4);

  hipMemsetAsync(cnt, 0, (size_t)N * 4, stream);
  k_prep_w<<<5 * C, C, 0, stream>>>(rel, root, WT);
  k_cvt_x<<<(rowsPad * C / 4 + 255) / 256, 256, 0, stream>>>(X, Xbf, N * C, rowsPad * C);
  k_hist<<<(E + 255) / 256, 256, 0, stream>>>(edst, cnt, E);
  int NB = (N + 511) / 512;
  k_scan1<<<NB, 512, 0, stream>>>(cnt, rp, bsum, N);
  k_scan2<<<1, 64, 0, stream>>>(bsum, boffb, rp, NB, N);
  k_scan3<<<NB, 512, 0, stream>>>(rp, boffb, N);
  hipMemcpyAsync(cursor, rp, (size_t)N * 4, hipMemcpyDeviceToDevice, stream);
  k_fill<<<(E + 255) / 256, 256, 0, stream>>>(esrc, edst, etype, cursor, sorted, E);
  k_gather<<<rowsPad / 4, 256, 0, stream>>>(Xbf, sorted, rp, agm, N, rowsPad);
  k_gemm<<<(rowsPad / BM) * 2, 256, 0, stream>>>(Aall, WT, bias, out, N, rowsPad);
  k_gate<<<(N + 3) / 4, 256, 0, stream>>>(X, aw, ab, out, N);
}

// Round 3
// 284.428 us; speedup vs baseline: 1.5341x; 1.1206x over previous
//
#include <hip/hip_runtime.h>
#include <hip/hip_bf16.h>

#define C 256
#define BM 128
#define BN 128
#define BK 32
#define NSTEP 40   // K = 5*256 / 32

typedef __attribute__((ext_vector_type(8))) short bf16x8;
typedef __attribute__((ext_vector_type(4))) float f32x4;
typedef __attribute__((ext_vector_type(4))) unsigned short us4;

#define GLL16(g, l)                                                         \
  __builtin_amdgcn_global_load_lds(                                         \
      (const __attribute__((address_space(1))) void*)(g),                   \
      (__attribute__((address_space(3))) void*)(l), 16, 0, 0)

__device__ __forceinline__ float bf2f(unsigned short u) {
  return __uint_as_float(((unsigned int)u) << 16);
}
__device__ __forceinline__ unsigned short f2bf(float f) {
  unsigned int x = __float_as_uint(f);
  unsigned int lsb = (x >> 16) & 1u;
  x += 0x7fffu + lsb;  // round-to-nearest-even
  return (unsigned short)(x >> 16);
}

// WT[m][c][k] = bf16(W_m[k][c]); m=0 -> root, m=1..4 -> rel r
__global__ void k_prep_w(const float* __restrict__ rel, const float* __restrict__ root,
                         unsigned short* __restrict__ WT) {
  int b = blockIdx.x;
  int m = b >> 8;
  int c = b & 255;
  int k = threadIdx.x;
  const float* W = (m == 0) ? root : (rel + (size_t)(m - 1) * C * C);
  WT[(size_t)m * C * C + (size_t)c * C + k] = f2bf(W[(size_t)k * C + c]);
}

__global__ void k_cvt_x(const float* __restrict__ X, unsigned short* __restrict__ Xbf,
                        int n_elem, int total) {
  int i = (blockIdx.x * blockDim.x + threadIdx.x) * 4;
  if (i >= total) return;
  us4 o;
  if (i < n_elem) {
    const float4 v = *reinterpret_cast<const float4*>(X + i);
    o.x = f2bf(v.x); o.y = f2bf(v.y); o.z = f2bf(v.z); o.w = f2bf(v.w);
  } else {
    o.x = 0; o.y = 0; o.z = 0; o.w = 0;   // zero pad rows
  }
  *reinterpret_cast<us4*>(Xbf + i) = o;
}

__global__ void k_hist(const int* __restrict__ edst, int* __restrict__ cnt, int E) {
  int e = blockIdx.x * blockDim.x + threadIdx.x;
  if (e < E) atomicAdd(cnt + edst[e], 1);
}

__global__ void k_scan1(const int* __restrict__ cnt, int* __restrict__ rp,
                        int* __restrict__ bsum, int n) {
  __shared__ int s[512];
  int t = threadIdx.x;
  int i = blockIdx.x * 512 + t;
  int v = (i < n) ? cnt[i] : 0;
  s[t] = v;
  __syncthreads();
  for (int off = 1; off < 512; off <<= 1) {
    int add = (t >= off) ? s[t - off] : 0;
    __syncthreads();
    s[t] += add;
    __syncthreads();
  }
  if (i < n) rp[i] = s[t] - v;
  if (t == 511) bsum[blockIdx.x] = s[511];
}

__global__ void k_scan2(const int* __restrict__ bsum, int* __restrict__ boff,
                        int* __restrict__ rp, int nb, int n) {
  if (threadIdx.x == 0) {
    int run = 0;
    for (int b = 0; b < nb; ++b) { boff[b] = run; run += bsum[b]; }
    rp[n] = run;
  }
}

__global__ void k_scan3(int* __restrict__ rp, const int* __restrict__ boff, int n) {
  int i = blockIdx.x * 512 + threadIdx.x;
  if (i < n) rp[i] += boff[blockIdx.x];
}

__global__ void k_fill(const int* __restrict__ esrc, const int* __restrict__ edst,
                       const int* __restrict__ etype, int* __restrict__ cursor,
                       unsigned int* __restrict__ sorted, int E) {
  int e = blockIdx.x * blockDim.x + threadIdx.x;
  if (e >= E) return;
  int d = edst[e];
  int pos = atomicAdd(cursor + d, 1);
  sorted[pos] = (unsigned int)esrc[e] | ((unsigned int)etype[e] << 28);
}

#define ACC(u, v)                                                            \
  do {                                                                       \
    float f0 = bf2f((v).x), f1 = bf2f((v).y), f2 = bf2f((v).z), f3 = bf2f((v).w); \
    switch ((u) >> 28) {                                                     \
      case 0: a0.x += f0; a0.y += f1; a0.z += f2; a0.w += f3; ++c0; break;   \
      case 1: a1.x += f0; a1.y += f1; a1.z += f2; a1.w += f3; ++c1; break;   \
      case 2: a2.x += f0; a2.y += f1; a2.z += f2; a2.w += f3; ++c2; break;   \
      default: a3.x += f0; a3.y += f1; a3.z += f2; a3.w += f3; ++c3; break;  \
    }                                                                        \
  } while (0)

// One wave per dst node: per-relation fp32 mean-accumulate of bf16 X rows, write bf16.
// Edge loop unrolled x4: 4 independent 512B row loads in flight per wave.
__global__ void k_gather(const unsigned short* __restrict__ Xbf,
                         const unsigned int* __restrict__ sorted,
                         const int* __restrict__ rp,
                         unsigned short* __restrict__ agm,
                         int N, int rowsPad) {
  int wave = threadIdx.x >> 6;
  int lane = threadIdx.x & 63;
  int dst = blockIdx.x * 4 + wave;
  if (dst >= rowsPad) return;

  if (dst >= N) {   // pad rows: zero so GEMM reads finite data
    us4 z; z.x = 0; z.y = 0; z.z = 0; z.w = 0;
    for (int r = 0; r < 4; ++r)
      *reinterpret_cast<us4*>(agm + ((size_t)r * rowsPad + dst) * C + lane * 4) = z;
    return;
  }

  float4 a0 = make_float4(0, 0, 0, 0), a1 = a0, a2 = a0, a3 = a0;
  int c0 = 0, c1 = 0, c2 = 0, c3 = 0;
  int s = rp[dst], e2 = rp[dst + 1];
  const us4* Xv = reinterpret_cast<const us4*>(Xbf);

  int e = s;
  for (; e + 4 <= e2; e += 4) {
    unsigned int u0 = sorted[e], u1 = sorted[e + 1], u2 = sorted[e + 2], u3 = sorted[e + 3];
    us4 v0 = Xv[(size_t)(u0 & 0x0FFFFFFFu) * 64 + lane];
    us4 v1 = Xv[(size_t)(u1 & 0x0FFFFFFFu) * 64 + lane];
    us4 v2 = Xv[(size_t)(u2 & 0x0FFFFFFFu) * 64 + lane];
    us4 v3 = Xv[(size_t)(u3 & 0x0FFFFFFFu) * 64 + lane];
    ACC(u0, v0); ACC(u1, v1); ACC(u2, v2); ACC(u3, v3);
  }
  for (; e < e2; ++e) {
    unsigned int u = sorted[e];
    us4 v = Xv[(size_t)(u & 0x0FFFFFFFu) * 64 + lane];
    ACC(u, v);
  }

  float s0 = 1.0f / (float)max(c0, 1);
  float s1 = 1.0f / (float)max(c1, 1);
  float s2 = 1.0f / (float)max(c2, 1);
  float s3 = 1.0f / (float)max(c3, 1);
  us4 o;
  size_t base = (size_t)dst * C + lane * 4;
  o.x = f2bf(a0.x * s0); o.y = f2bf(a0.y * s0); o.z = f2bf(a0.z * s0); o.w = f2bf(a0.w * s0);
  *reinterpret_cast<us4*>(agm + base) = o;
  o.x = f2bf(a1.x * s1); o.y = f2bf(a1.y * s1); o.z = f2bf(a1.z * s1); o.w = f2bf(a1.w * s1);
  *reinterpret_cast<us4*>(agm + (size_t)rowsPad * C + base) = o;
  o.x = f2bf(a2.x * s2); o.y = f2bf(a2.y * s2); o.z = f2bf(a2.z * s2); o.w = f2bf(a2.w * s2);
  *reinterpret_cast<us4*>(agm + (size_t)2 * rowsPad * C + base) = o;
  o.x = f2bf(a3.x * s3); o.y = f2bf(a3.y * s3); o.z = f2bf(a3.z * s3); o.w = f2bf(a3.w * s3);
  *reinterpret_cast<us4*>(agm + (size_t)3 * rowsPad * C + base) = o;
}

// One K=1280 GEMM: out = A_all @ WT^T + bias, A_all = [5][rowsPad][256] bf16.
// m97 structure + bijective chunked XCD swizzle so the (m, n=0/1) pair shares
// its A panel in one XCD's L2.
__global__ __launch_bounds__(256) void k_gemm(const unsigned short* __restrict__ Aall,
                                              const unsigned short* __restrict__ WT,
                                              const float* __restrict__ bias,
                                              float* __restrict__ out, int N, int rowsPad) {
  __shared__ unsigned short lds_a[BM * BK];
  __shared__ unsigned short lds_b[BN * BK];
  int tid = threadIdx.x;
  int wave = tid >> 6, lane = tid & 63;

  // bijective chunked XCD swizzle (m204): orig round-robin pos -> chunked id
  int nwg = gridDim.x;
  int orig = blockIdx.x;
  int q = nwg >> 3, r = nwg & 7;
  int xcd = orig & 7, lin = orig >> 3;
  int wgid = (xcd < r ? xcd * (q + 1) : r * (q + 1) + (xcd - r) * q) + lin;

  int mblk = wgid >> 1, nblk = wgid & 1;
  int row0 = mblk * BM, col0 = nblk * BN;
  int wr = wave >> 1, wc = wave & 1;

  // staging geometry (loop-invariant): each wave stages 2 chunks of A + 2 of B
  int rowS[2], lg8[2];
#pragma unroll
  for (int c2 = 0; c2 < 2; ++c2) {
    int off = (wave * 2 + c2) * 1024 + lane * 16;   // phys byte in tile
    int rr = off >> 6;                               // tile row (64B rows)
    int lg = ((off >> 4) & 3) ^ (rr & 3);            // logical 16B granule
    rowS[c2] = rr;
    lg8[c2] = lg * 8;                                // element offset
  }

  // ds_read byte offsets (loop-invariant, swizzled)
  int aoff[4], boff[4];
  int kb = (lane >> 4) * 16;
#pragma unroll
  for (int i = 0; i < 4; ++i) {
    int ar = wr * 64 + i * 16 + (lane & 15);
    aoff[i] = ar * 64 + (kb ^ ((ar & 3) << 4));
    int bc = wc * 64 + i * 16 + (lane & 15);
    boff[i] = bc * 64 + (kb ^ ((bc & 3) << 4));
  }

  f32x4 acc[4][4];
#pragma unroll
  for (int i = 0; i < 4; ++i)
#pragma unroll
    for (int j = 0; j < 4; ++j) {
      f32x4 z; z[0] = 0.f; z[1] = 0.f; z[2] = 0.f; z[3] = 0.f;
      acc[i][j] = z;
    }

#pragma unroll 1
  for (int ks = 0; ks < NSTEP; ++ks) {
    int m = ks >> 3;
    int kk = (ks & 7) * BK;
    const unsigned short* Ab = Aall + (size_t)m * rowsPad * C + kk;
    const unsigned short* Bb = WT + (size_t)m * C * C + kk;
#pragma unroll
    for (int c2 = 0; c2 < 2; ++c2) {
      const unsigned short* sa = Ab + (size_t)(row0 + rowS[c2]) * C + lg8[c2];
      const unsigned short* sb = Bb + (size_t)(col0 + rowS[c2]) * C + lg8[c2];
      GLL16(sa, (char*)lds_a + (wave * 2 + c2) * 1024);
      GLL16(sb, (char*)lds_b + (wave * 2 + c2) * 1024);
    }
    __syncthreads();   // drains vmcnt -> staged tiles visible
    bf16x8 af[4], bfr[4];
#pragma unroll
    for (int i = 0; i < 4; ++i) {
      af[i]  = *reinterpret_cast<const bf16x8*>((const char*)lds_a + aoff[i]);
      bfr[i] = *reinterpret_cast<const bf16x8*>((const char*)lds_b + boff[i]);
    }
#pragma unroll
    for (int mr = 0; mr < 4; ++mr)
#pragma unroll
      for (int nc = 0; nc < 4; ++nc)
        acc[mr][nc] = __builtin_amdgcn_mfma_f32_16x16x32_bf16(af[mr], bfr[nc], acc[mr][nc], 0, 0, 0);
    __syncthreads();   // all waves done reading before next overwrite
  }

  int lcol = lane & 15, lrow4 = (lane >> 4) * 4;
#pragma unroll
  for (int mr = 0; mr < 4; ++mr) {
#pragma unroll
    for (int reg = 0; reg < 4; ++reg) {
      int rowg = row0 + wr * 64 + mr * 16 + lrow4 + reg;
      if (rowg < N) {
#pragma unroll
        for (int nc = 0; nc < 4; ++nc) {
          int colg = col0 + wc * 64 + nc * 16 + lcol;
          out[(size_t)rowg * C + colg] = acc[mr][nc][reg] + bias[colg];
        }
      }
    }
  }
}

// Gate: a = sigmoid(u0.w1 + x.w2 + b); h = tanh(u0)*a + x*(1-a). One wave per node, in place.
__global__ void k_gate(const float* __restrict__ X, const float* __restrict__ aw,
                       const float* __restrict__ ab, float* __restrict__ out, int N) {
  int wave = threadIdx.x >> 6, lane = threadIdx.x & 63;
  int node = blockIdx.x * 4 + wave;
  if (node >= N) return;
  const float4* u4 = reinterpret_cast<const float4*>(out + (size_t)node * C);
  const float4* x4 = reinterpret_cast<const float4*>(X + (size_t)node * C);
  float4 u = u4[lane], x = x4[lane];
  const float4* w = reinterpret_cast<const float4*>(aw);
  float4 w1 = w[lane], w2 = w[64 + lane];
  float p = u.x * w1.x + u.y * w1.y + u.z * w1.z + u.w * w1.w
          + x.x * w2.x + x.y * w2.y + x.z * w2.z + x.w * w2.w;
#pragma unroll
  for (int off = 32; off >= 1; off >>= 1) p += __shfl_xor(p, off);
  float a = 1.0f / (1.0f + expf(-(p + ab[0])));
  float b = 1.0f - a;
  float4 h;
  h.x = tanhf(u.x) * a + x.x * b;
  h.y = tanhf(u.y) * a + x.y * b;
  h.z = tanhf(u.z) * a + x.z * b;
  h.w = tanhf(u.w) * a + x.w * b;
  reinterpret_cast<float4*>(out + (size_t)node * C)[lane] = h;
}

extern "C" void kernel_launch(void* const* d_in, const int* in_sizes, int n_in,
                              void* d_out, int out_size, void* d_ws, size_t ws_size,
                              hipStream_t stream) {
  const float* X     = (const float*)d_in[0];
  const int*   eidx  = (const int*)d_in[1];
  const int*   etype = (const int*)d_in[2];
  const float* rel   = (const float*)d_in[3];
  const float* root  = (const float*)d_in[4];
  const float* bias  = (const float*)d_in[5];
  const float* aw    = (const float*)d_in[6];
  const float* ab    = (const float*)d_in[7];
  float* out = (float*)d_out;

  int N = in_sizes[0] / C;                // 50000
  int E = in_sizes[2];                    // 800000
  int rowsPad = ((N + 127) / 128) * 128;  // 50048
  const int* esrc = eidx;
  const int* edst = eidx + E;

  char* w = (char*)d_ws;
  size_t off = 0;
  auto alloc = [&](size_t bytes) -> void* {
    void* p = w + off;
    off += (bytes + 255) & ~(size_t)255;
    return p;
  };
  // A_all = [5][rowsPad][C] bf16; m=0 is X, m=1..4 are per-relation means
  unsigned short* Aall = (unsigned short*)alloc((size_t)5 * rowsPad * C * 2);
  unsigned short* Xbf  = Aall;
  unsigned short* agm  = Aall + (size_t)rowsPad * C;
  unsigned short* WT   = (unsigned short*)alloc((size_t)5 * C * C * 2);
  int* cnt    = (int*)alloc((size_t)N * 4);
  int* rp     = (int*)alloc((size_t)(N + 1) * 4);
  int* cursor = (int*)alloc((size_t)N * 4);
  int* bsum   = (int*)alloc(1024);
  int* boffb  = (int*)alloc(1024);
  unsigned int* sorted = (unsigned int*)alloc((size_t)E * 4);

  hipMemsetAsync(cnt, 0, (size_t)N * 4, stream);
  k_prep_w<<<5 * C, C, 0, stream>>>(rel, root, WT);
  k_cvt_x<<<(rowsPad * C / 4 + 255) / 256, 256, 0, stream>>>(X, Xbf, N * C, rowsPad * C);
  k_hist<<<(E + 255) / 256, 256, 0, stream>>>(edst, cnt, E);
  int NB = (N + 511) / 512;
  k_scan1<<<NB, 512, 0, stream>>>(cnt, rp, bsum, N);
  k_scan2<<<1, 64, 0, stream>>>(bsum, boffb, rp, NB, N);
  k_scan3<<<NB, 512, 0, stream>>>(rp, boffb, N);
  hipMemcpyAsync(cursor, rp, (size_t)N * 4, hipMemcpyDeviceToDevice, stream);
  k_fill<<<(E + 255) / 256, 256, 0, stream>>>(esrc, edst, etype, cursor, sorted, E);
  k_gather<<<rowsPad / 4, 256, 0, stream>>>(Xbf, sorted, rp, agm, N, rowsPad);
  k_gemm<<<(rowsPad / BM) * 2, 256, 0, stream>>>(Aall, WT, bias, out, N, rowsPad);
  k_gate<<<(N + 3) / 4, 256, 0, stream>>>(X, aw, ab, out, N);
}

// Round 4
// 271.233 us; speedup vs baseline: 1.6088x; 1.0487x over previous
//
#include <hip/hip_runtime.h>
#include <hip/hip_bf16.h>

#define C 256
#define BM 64
#define BN 128
#define BK 32
#define NSTEP 40   // K = 5*256 / 32

typedef __attribute__((ext_vector_type(8))) short bf16x8;
typedef __attribute__((ext_vector_type(4))) float f32x4;
typedef __attribute__((ext_vector_type(4))) unsigned short us4;

#define GLL16(g, l)                                                         \
  __builtin_amdgcn_global_load_lds(                                         \
      (const __attribute__((address_space(1))) void*)(g),                   \
      (__attribute__((address_space(3))) void*)(l), 16, 0, 0)

__device__ __forceinline__ float bf2f(unsigned short u) {
  return __uint_as_float(((unsigned int)u) << 16);
}
__device__ __forceinline__ unsigned short f2bf(float f) {
  unsigned int x = __float_as_uint(f);
  unsigned int lsb = (x >> 16) & 1u;
  x += 0x7fffu + lsb;  // round-to-nearest-even
  return (unsigned short)(x >> 16);
}

// WT[m][c][k] = bf16(W_m[k][c]); m=0 -> root, m=1..4 -> rel r
__global__ void k_prep_w(const float* __restrict__ rel, const float* __restrict__ root,
                         unsigned short* __restrict__ WT) {
  int b = blockIdx.x;
  int m = b >> 8;
  int c = b & 255;
  int k = threadIdx.x;
  const float* W = (m == 0) ? root : (rel + (size_t)(m - 1) * C * C);
  WT[(size_t)m * C * C + (size_t)c * C + k] = f2bf(W[(size_t)k * C + c]);
}

__global__ void k_cvt_x(const float* __restrict__ X, unsigned short* __restrict__ Xbf,
                        int n_elem, int total) {
  int i = (blockIdx.x * blockDim.x + threadIdx.x) * 4;
  if (i >= total) return;
  us4 o;
  if (i < n_elem) {
    const float4 v = *reinterpret_cast<const float4*>(X + i);
    o.x = f2bf(v.x); o.y = f2bf(v.y); o.z = f2bf(v.z); o.w = f2bf(v.w);
  } else {
    o.x = 0; o.y = 0; o.z = 0; o.w = 0;   // zero pad rows
  }
  *reinterpret_cast<us4*>(Xbf + i) = o;
}

__global__ void k_hist(const int* __restrict__ edst, int* __restrict__ cnt, int E) {
  int e = blockIdx.x * blockDim.x + threadIdx.x;
  if (e < E) atomicAdd(cnt + edst[e], 1);
}

__global__ void k_scan1(const int* __restrict__ cnt, int* __restrict__ rp,
                        int* __restrict__ bsum, int n) {
  __shared__ int s[512];
  int t = threadIdx.x;
  int i = blockIdx.x * 512 + t;
  int v = (i < n) ? cnt[i] : 0;
  s[t] = v;
  __syncthreads();
  for (int off = 1; off < 512; off <<= 1) {
    int add = (t >= off) ? s[t - off] : 0;
    __syncthreads();
    s[t] += add;
    __syncthreads();
  }
  if (i < n) rp[i] = s[t] - v;
  if (t == 511) bsum[blockIdx.x] = s[511];
}

__global__ void k_scan2(const int* __restrict__ bsum, int* __restrict__ boff,
                        int* __restrict__ rp, int nb, int n) {
  if (threadIdx.x == 0) {
    int run = 0;
    for (int b = 0; b < nb; ++b) { boff[b] = run; run += bsum[b]; }
    rp[n] = run;
  }
}

__global__ void k_scan3(int* __restrict__ rp, const int* __restrict__ boff, int n) {
  int i = blockIdx.x * 512 + threadIdx.x;
  if (i < n) rp[i] += boff[blockIdx.x];
}

__global__ void k_fill(const int* __restrict__ esrc, const int* __restrict__ edst,
                       const int* __restrict__ etype, int* __restrict__ cursor,
                       unsigned int* __restrict__ sorted, int E) {
  int e = blockIdx.x * blockDim.x + threadIdx.x;
  if (e >= E) return;
  int d = edst[e];
  int pos = atomicAdd(cursor + d, 1);
  sorted[pos] = (unsigned int)esrc[e] | ((unsigned int)etype[e] << 28);
}

#define ACC(u, v)                                                            \
  do {                                                                       \
    float f0 = bf2f((v).x), f1 = bf2f((v).y), f2 = bf2f((v).z), f3 = bf2f((v).w); \
    switch ((u) >> 28) {                                                     \
      case 0: a0.x += f0; a0.y += f1; a0.z += f2; a0.w += f3; ++c0; break;   \
      case 1: a1.x += f0; a1.y += f1; a1.z += f2; a1.w += f3; ++c1; break;   \
      case 2: a2.x += f0; a2.y += f1; a2.z += f2; a2.w += f3; ++c2; break;   \
      default: a3.x += f0; a3.y += f1; a3.z += f2; a3.w += f3; ++c3; break;  \
    }                                                                        \
  } while (0)

// One wave per dst node; per-relation fp32 mean-accumulate of bf16 X rows.
// Edge loop unrolled x8: 8 independent 512B row loads in flight per wave.
__global__ void k_gather(const unsigned short* __restrict__ Xbf,
                         const unsigned int* __restrict__ sorted,
                         const int* __restrict__ rp,
                         unsigned short* __restrict__ agm,
                         int N, int rowsPad) {
  int wave = threadIdx.x >> 6;
  int lane = threadIdx.x & 63;
  int dst = blockIdx.x * 4 + wave;
  if (dst >= rowsPad) return;

  if (dst >= N) {   // pad rows: zero so GEMM reads finite data
    us4 z; z.x = 0; z.y = 0; z.z = 0; z.w = 0;
    for (int r = 0; r < 4; ++r)
      *reinterpret_cast<us4*>(agm + ((size_t)r * rowsPad + dst) * C + lane * 4) = z;
    return;
  }

  float4 a0 = make_float4(0, 0, 0, 0), a1 = a0, a2 = a0, a3 = a0;
  int c0 = 0, c1 = 0, c2 = 0, c3 = 0;
  int s = rp[dst], e2 = rp[dst + 1];
  const us4* Xv = reinterpret_cast<const us4*>(Xbf);

  int e = s;
  for (; e + 8 <= e2; e += 8) {
    unsigned int u0 = sorted[e],     u1 = sorted[e + 1], u2 = sorted[e + 2], u3 = sorted[e + 3];
    unsigned int u4 = sorted[e + 4], u5 = sorted[e + 5], u6 = sorted[e + 6], u7 = sorted[e + 7];
    us4 v0 = Xv[(size_t)(u0 & 0x0FFFFFFFu) * 64 + lane];
    us4 v1 = Xv[(size_t)(u1 & 0x0FFFFFFFu) * 64 + lane];
    us4 v2 = Xv[(size_t)(u2 & 0x0FFFFFFFu) * 64 + lane];
    us4 v3 = Xv[(size_t)(u3 & 0x0FFFFFFFu) * 64 + lane];
    us4 v4 = Xv[(size_t)(u4 & 0x0FFFFFFFu) * 64 + lane];
    us4 v5 = Xv[(size_t)(u5 & 0x0FFFFFFFu) * 64 + lane];
    us4 v6 = Xv[(size_t)(u6 & 0x0FFFFFFFu) * 64 + lane];
    us4 v7 = Xv[(size_t)(u7 & 0x0FFFFFFFu) * 64 + lane];
    ACC(u0, v0); ACC(u1, v1); ACC(u2, v2); ACC(u3, v3);
    ACC(u4, v4); ACC(u5, v5); ACC(u6, v6); ACC(u7, v7);
  }
  for (; e + 4 <= e2; e += 4) {
    unsigned int u0 = sorted[e], u1 = sorted[e + 1], u2 = sorted[e + 2], u3 = sorted[e + 3];
    us4 v0 = Xv[(size_t)(u0 & 0x0FFFFFFFu) * 64 + lane];
    us4 v1 = Xv[(size_t)(u1 & 0x0FFFFFFFu) * 64 + lane];
    us4 v2 = Xv[(size_t)(u2 & 0x0FFFFFFFu) * 64 + lane];
    us4 v3 = Xv[(size_t)(u3 & 0x0FFFFFFFu) * 64 + lane];
    ACC(u0, v0); ACC(u1, v1); ACC(u2, v2); ACC(u3, v3);
  }
  for (; e < e2; ++e) {
    unsigned int u = sorted[e];
    us4 v = Xv[(size_t)(u & 0x0FFFFFFFu) * 64 + lane];
    ACC(u, v);
  }

  float s0 = 1.0f / (float)max(c0, 1);
  float s1 = 1.0f / (float)max(c1, 1);
  float s2 = 1.0f / (float)max(c2, 1);
  float s3 = 1.0f / (float)max(c3, 1);
  us4 o;
  size_t base = (size_t)dst * C + lane * 4;
  o.x = f2bf(a0.x * s0); o.y = f2bf(a0.y * s0); o.z = f2bf(a0.z * s0); o.w = f2bf(a0.w * s0);
  *reinterpret_cast<us4*>(agm + base) = o;
  o.x = f2bf(a1.x * s1); o.y = f2bf(a1.y * s1); o.z = f2bf(a1.z * s1); o.w = f2bf(a1.w * s1);
  *reinterpret_cast<us4*>(agm + (size_t)rowsPad * C + base) = o;
  o.x = f2bf(a2.x * s2); o.y = f2bf(a2.y * s2); o.z = f2bf(a2.z * s2); o.w = f2bf(a2.w * s2);
  *reinterpret_cast<us4*>(agm + (size_t)2 * rowsPad * C + base) = o;
  o.x = f2bf(a3.x * s3); o.y = f2bf(a3.y * s3); o.z = f2bf(a3.z * s3); o.w = f2bf(a3.w * s3);
  *reinterpret_cast<us4*>(agm + (size_t)3 * rowsPad * C + base) = o;
}

// One K=1280 GEMM: out = A_all @ WT^T + bias.
// 2-phase double-buffered pipeline (T3 minimum): stage tile k+1 before
// computing tile k, ONE barrier per K-step. BM=64 x BN=128 -> 1564 blocks
// (6.1/CU). LDS swizzle: slot(r)=(4r+g)%8 with g=(r>>1)&3 covers all 8
// 16B-slots per 8 rows -> 2-way (free). Same XOR on store-source and read.
__global__ __launch_bounds__(256) void k_gemm(const unsigned short* __restrict__ Aall,
                                              const unsigned short* __restrict__ WT,
                                              const float* __restrict__ bias,
                                              float* __restrict__ out, int N, int rowsPad) {
  __shared__ unsigned short lds_a[2][BM * BK];   // 2 x 4KB
  __shared__ unsigned short lds_b[2][BN * BK];   // 2 x 8KB
  int tid = threadIdx.x;
  int wave = tid >> 6, lane = tid & 63;

  // bijective chunked XCD swizzle (m204)
  int nwg = gridDim.x;
  int orig = blockIdx.x;
  int q = nwg >> 3, r = nwg & 7;
  int xcd = orig & 7, lin = orig >> 3;
  int wgid = (xcd < r ? xcd * (q + 1) : r * (q + 1) + (xcd - r) * q) + lin;

  int mblk = wgid >> 1, nblk = wgid & 1;
  int row0 = mblk * BM, col0 = nblk * BN;
  int wr = wave >> 1, wc = wave & 1;

  // staging geometry: wave w stages A chunk w (1KB), B chunks 2w, 2w+1
  int offA = wave * 1024 + lane * 16;
  int arS = offA >> 6;
  int alg8 = ((((offA >> 4) & 3) ^ ((arS >> 1) & 3))) * 8;
  int brS[2], blg8[2];
#pragma unroll
  for (int c2 = 0; c2 < 2; ++c2) {
    int off = (wave * 2 + c2) * 1024 + lane * 16;
    int rr = off >> 6;
    brS[c2] = rr;
    blg8[c2] = ((((off >> 4) & 3) ^ ((rr >> 1) & 3))) * 8;
  }

  // ds_read byte offsets (swizzled, loop-invariant)
  int aoff[2], boff[4];
  int kb = (lane >> 4) * 16;
#pragma unroll
  for (int i = 0; i < 2; ++i) {
    int ar = wr * 32 + i * 16 + (lane & 15);
    aoff[i] = ar * 64 + (kb ^ (((ar >> 1) & 3) << 4));
  }
#pragma unroll
  for (int j = 0; j < 4; ++j) {
    int bc = wc * 64 + j * 16 + (lane & 15);
    boff[j] = bc * 64 + (kb ^ (((bc >> 1) & 3) << 4));
  }

  f32x4 acc[2][4];
#pragma unroll
  for (int i = 0; i < 2; ++i)
#pragma unroll
    for (int j = 0; j < 4; ++j) {
      f32x4 z; z[0] = 0.f; z[1] = 0.f; z[2] = 0.f; z[3] = 0.f;
      acc[i][j] = z;
    }

  auto stage = [&](int buf, int ks) {
    int m = ks >> 3;
    int kk = (ks & 7) * BK;
    const unsigned short* Ab = Aall + (size_t)m * rowsPad * C + kk;
    const unsigned short* Bb = WT + (size_t)m * C * C + kk;
    GLL16(Ab + (size_t)(row0 + arS) * C + alg8, (char*)&lds_a[buf][0] + wave * 1024);
#pragma unroll
    for (int c2 = 0; c2 < 2; ++c2)
      GLL16(Bb + (size_t)(col0 + brS[c2]) * C + blg8[c2],
            (char*)&lds_b[buf][0] + (wave * 2 + c2) * 1024);
  };

  stage(0, 0);
  __syncthreads();   // tile 0 resident

#pragma unroll 1
  for (int ks = 0; ks < NSTEP; ++ks) {
    int cur = ks & 1;
    if (ks + 1 < NSTEP) stage(cur ^ 1, ks + 1);   // issue next-tile loads early
    bf16x8 af[2], bfr[4];
#pragma unroll
    for (int i = 0; i < 2; ++i)
      af[i] = *reinterpret_cast<const bf16x8*>((const char*)&lds_a[cur][0] + aoff[i]);
#pragma unroll
    for (int j = 0; j < 4; ++j)
      bfr[j] = *reinterpret_cast<const bf16x8*>((const char*)&lds_b[cur][0] + boff[j]);
#pragma unroll
    for (int mr = 0; mr < 2; ++mr)
#pragma unroll
      for (int nc = 0; nc < 4; ++nc)
        acc[mr][nc] = __builtin_amdgcn_mfma_f32_16x16x32_bf16(af[mr], bfr[nc], acc[mr][nc], 0, 0, 0);
    __syncthreads();   // drains vmcnt (next tile ready) + reads done before overwrite
  }

  int lcol = lane & 15, lrow4 = (lane >> 4) * 4;
#pragma unroll
  for (int mr = 0; mr < 2; ++mr) {
#pragma unroll
    for (int reg = 0; reg < 4; ++reg) {
      int rowg = row0 + wr * 32 + mr * 16 + lrow4 + reg;
      if (rowg < N) {
#pragma unroll
        for (int nc = 0; nc < 4; ++nc) {
          int colg = col0 + wc * 64 + nc * 16 + lcol;
          out[(size_t)rowg * C + colg] = acc[mr][nc][reg] + bias[colg];
        }
      }
    }
  }
}

// Gate: a = sigmoid(u0.w1 + x.w2 + b); h = tanh(u0)*a + x*(1-a). One wave per node, in place.
__global__ void k_gate(const float* __restrict__ X, const float* __restrict__ aw,
                       const float* __restrict__ ab, float* __restrict__ out, int N) {
  int wave = threadIdx.x >> 6, lane = threadIdx.x & 63;
  int node = blockIdx.x * 4 + wave;
  if (node >= N) return;
  const float4* u4 = reinterpret_cast<const float4*>(out + (size_t)node * C);
  const float4* x4 = reinterpret_cast<const float4*>(X + (size_t)node * C);
  float4 u = u4[lane], x = x4[lane];
  const float4* w = reinterpret_cast<const float4*>(aw);
  float4 w1 = w[lane], w2 = w[64 + lane];
  float p = u.x * w1.x + u.y * w1.y + u.z * w1.z + u.w * w1.w
          + x.x * w2.x + x.y * w2.y + x.z * w2.z + x.w * w2.w;
#pragma unroll
  for (int off = 32; off >= 1; off >>= 1) p += __shfl_xor(p, off);
  float a = 1.0f / (1.0f + expf(-(p + ab[0])));
  float b = 1.0f - a;
  float4 h;
  h.x = tanhf(u.x) * a + x.x * b;
  h.y = tanhf(u.y) * a + x.y * b;
  h.z = tanhf(u.z) * a + x.z * b;
  h.w = tanhf(u.w) * a + x.w * b;
  reinterpret_cast<float4*>(out + (size_t)node * C)[lane] = h;
}

extern "C" void kernel_launch(void* const* d_in, const int* in_sizes, int n_in,
                              void* d_out, int out_size, void* d_ws, size_t ws_size,
                              hipStream_t stream) {
  const float* X     = (const float*)d_in[0];
  const int*   eidx  = (const int*)d_in[1];
  const int*   etype = (const int*)d_in[2];
  const float* rel   = (const float*)d_in[3];
  const float* root  = (const float*)d_in[4];
  const float* bias  = (const float*)d_in[5];
  const float* aw    = (const float*)d_in[6];
  const float* ab    = (const float*)d_in[7];
  float* out = (float*)d_out;

  int N = in_sizes[0] / C;                // 50000
  int E = in_sizes[2];                    // 800000
  int rowsPad = ((N + 127) / 128) * 128;  // 50048 (divisible by 64 and 128)
  const int* esrc = eidx;
  const int* edst = eidx + E;

  char* w = (char*)d_ws;
  size_t off = 0;
  auto alloc = [&](size_t bytes) -> void* {
    void* p = w + off;
    off += (bytes + 255) & ~(size_t)255;
    return p;
  };
  // A_all = [5][rowsPad][C] bf16; m=0 is X, m=1..4 are per-relation means
  unsigned short* Aall = (unsigned short*)alloc((size_t)5 * rowsPad * C * 2);
  unsigned short* Xbf  = Aall;
  unsigned short* agm  = Aall + (size_t)rowsPad * C;
  unsigned short* WT   = (unsigned short*)alloc((size_t)5 * C * C * 2);
  int* cnt    = (int*)alloc((size_t)N * 4);
  int* rp     = (int*)alloc((size_t)(N + 1) * 4);
  int* cursor = (int*)alloc((size_t)N * 4);
  int* bsum   = (int*)alloc(1024);
  int* boffb  = (int*)alloc(1024);
  unsigned int* sorted = (unsigned int*)alloc((size_t)E * 4);

  hipMemsetAsync(cnt, 0, (size_t)N * 4, stream);
  k_prep_w<<<5 * C, C, 0, stream>>>(rel, root, WT);
  k_cvt_x<<<(rowsPad * C / 4 + 255) / 256, 256, 0, stream>>>(X, Xbf, N * C, rowsPad * C);
  k_hist<<<(E + 255) / 256, 256, 0, stream>>>(edst, cnt, E);
  int NB = (N + 511) / 512;
  k_scan1<<<NB, 512, 0, stream>>>(cnt, rp, bsum, N);
  k_scan2<<<1, 64, 0, stream>>>(bsum, boffb, rp, NB, N);
  k_scan3<<<NB, 512, 0, stream>>>(rp, boffb, N);
  hipMemcpyAsync(cursor, rp, (size_t)N * 4, hipMemcpyDeviceToDevice, stream);
  k_fill<<<(E + 255) / 256, 256, 0, stream>>>(esrc, edst, etype, cursor, sorted, E);
  k_gather<<<rowsPad / 4, 256, 0, stream>>>(Xbf, sorted, rp, agm, N, rowsPad);
  k_gemm<<<(rowsPad / BM) * 2, 256, 0, stream>>>(Aall, WT, bias, out, N, rowsPad);
  k_gate<<<(N + 3) / 4, 256, 0, stream>>>(X, aw, ab, out, N);
}